// Round 4
// baseline (966.258 us; speedup 1.0000x reference)
//
#include <hip/hip_runtime.h>
#include <math.h>

// NeuReparam: fused posenc + 20->64->64->64->64->3 SiLU MLP forward + 2 JVPs
// (Jacobian columns wrt z) + normalize epilogue + detJ.
//
// Parallelization: 6 waves per 64-sample group = 3 states (primal, dz0, dz1)
// x 2 output-halves (j in [0,32) / [32,64)). Block = 384 threads.
// LDS layout [channel][sample] (stride-1 across lanes -> 2-way aliasing, free).
//
// Structure (9 barriers total):
//   input : ALL waves compute posenc + 20x32 matmul redundantly (no idle);
//           primal writes h_in, tangents form t_in locally. 1 barrier.
//   L0    : Phase A reads plain src (h_in / t_in); sync; primal writes h,sp;
//           tangents write raw u = W*t; sync.                2 barriers
//   L1,L2 : tangent source fused on the fly: t[k]=sp[k]*u[k]. 2 barriers each
//   out   : all 6 waves, k-range split by half; partials staged in LDS;
//           wave0 does softplus/normalize/detJ epilogue.     2 barriers
//
// Weight addresses are wave-uniform (readfirstlane on wave) -> s_load (SMEM)
// weight reads; inner loop = ds_read + 32 v_fmac with SGPR weight operands.
// Transcendentals use HW intrinsics (v_sin/v_cos/v_exp/v_rcp) - the IEEE
// div/ocml versions cost ~10 insts each on the barrier-to-barrier critical
// path. Epilogue (1 wave, detJ) keeps full-precision math.

#define SAMP 64
#define NTHR 384
#define C 64

__device__ __forceinline__ float frcp(float x) { return __builtin_amdgcn_rcpf(x); }
__device__ __forceinline__ float fsig(float a) { return frcp(1.f + __expf(-a)); }

__global__ __launch_bounds__(NTHR, 1) void neu_kernel(
    const float* __restrict__ wo, const float* __restrict__ z,
    const float* __restrict__ W_in, const float* __restrict__ b_in,
    const float* __restrict__ W_hid, const float* __restrict__ b_hid,
    const float* __restrict__ W_out, const float* __restrict__ b_out,
    float* __restrict__ out)
{
    __shared__ float sh_h [C*SAMP];      // primal activations (current layer)
    __shared__ float sh_sp[C*SAMP];      // silu'(a) of current layer
    __shared__ float sh_t0[C*SAMP];      // dz0 state: t_in, then u_l = W*t
    __shared__ float sh_t1[C*SAMP];      // dz1 state
    __shared__ float sh_st[18*SAMP];     // output partial staging (6 waves x 3)

    const int tid   = threadIdx.x;
    const int samp  = tid & 63;
    // Force wave-role scalars into SGPRs so weight addressing is provably
    // uniform (s_load) and role branches are scalar (s_cbranch).
    const int wave  = __builtin_amdgcn_readfirstlane(tid >> 6);  // 0..5
    const int state = wave >> 1;          // 0 primal, 1 dz0, 2 dz1
    const int half  = wave & 1;
    const int jb    = half * 32;
    const int gs    = blockIdx.x * SAMP + samp;

    float* myT = (state == 1) ? sh_t0 : sh_t1;   // tangent state buffer

    float acc[32];

    // ---------------- input layer (ALL waves) ----------------
    {
        float x[20];
        const float2 wv = *reinterpret_cast<const float2*>(wo + gs*2);
        x[0] = wv.x; x[1] = wv.y;
        float f0 = wv.x, f1 = wv.y;
        #pragma unroll
        for (int i = 0; i < 4; ++i) {
            x[2+4*i+0] = __sinf(f0);        // v_sin; args < 1.3 revolutions
            x[2+4*i+1] = __sinf(f1);
            x[2+4*i+2] = __cosf(f0);
            x[2+4*i+3] = __cosf(f1);
            f0 += f0; f1 += f1;
        }
        const float2 zv = *reinterpret_cast<const float2*>(z + gs*2);
        x[18] = zv.x;
        x[19] = zv.y;

        #pragma unroll
        for (int j = 0; j < 32; ++j) acc[j] = b_in[jb+j];
        #pragma unroll
        for (int k = 0; k < 20; ++k) {
            const float xk = x[k];
            const float* wr = W_in + k*C + jb;
            #pragma unroll
            for (int j = 0; j < 32; ++j) acc[j] = fmaf(xk, wr[j], acc[j]);
        }
        if (state == 0) {
            #pragma unroll
            for (int j = 0; j < 32; ++j) {
                float a  = acc[j];
                float sg = fsig(a);
                sh_h[(jb+j)*SAMP + samp] = a * sg;
            }
        } else {
            const float* wr = W_in + (18 + state - 1)*C + jb;
            #pragma unroll
            for (int j = 0; j < 32; ++j) {
                float a  = acc[j];
                float sg = fsig(a);
                float sp = sg * (1.f + a * (1.f - sg));
                myT[(jb+j)*SAMP + samp] = sp * wr[j];
            }
        }
    }
    __syncthreads();

    // ---------------- hidden layers ----------------
    #pragma unroll
    for (int l = 0; l < 3; ++l) {
        const float* Wl = W_hid + l*C*C + jb;
        if (state == 0) {
            #pragma unroll
            for (int j = 0; j < 32; ++j) acc[j] = b_hid[l*C + jb + j];
            #pragma unroll 2
            for (int k = 0; k < C; ++k) {
                const float m  = sh_h[k*SAMP + samp];
                const float* wr = Wl + k*C;
                #pragma unroll
                for (int j = 0; j < 32; ++j) acc[j] = fmaf(m, wr[j], acc[j]);
            }
        } else {
            #pragma unroll
            for (int j = 0; j < 32; ++j) acc[j] = 0.f;
            if (l == 0) {       // plain t_in source
                #pragma unroll 2
                for (int k = 0; k < C; ++k) {
                    const float m  = myT[k*SAMP + samp];
                    const float* wr = Wl + k*C;
                    #pragma unroll
                    for (int j = 0; j < 32; ++j) acc[j] = fmaf(m, wr[j], acc[j]);
                }
            } else {            // fused t[k] = sp[k] * u[k]
                #pragma unroll 2
                for (int k = 0; k < C; ++k) {
                    const float m  = sh_sp[k*SAMP + samp] * myT[k*SAMP + samp];
                    const float* wr = Wl + k*C;
                    #pragma unroll
                    for (int j = 0; j < 32; ++j) acc[j] = fmaf(m, wr[j], acc[j]);
                }
            }
        }
        __syncthreads();   // sync_a: all Phase-A reads of layer-l state done
        if (state == 0) {
            #pragma unroll
            for (int j = 0; j < 32; ++j) {
                float a  = acc[j];
                float sg = fsig(a);
                sh_h [(jb+j)*SAMP + samp] = a * sg;
                sh_sp[(jb+j)*SAMP + samp] = sg * (1.f + a * (1.f - sg));
            }
        } else {
            #pragma unroll
            for (int j = 0; j < 32; ++j) myT[(jb+j)*SAMP + samp] = acc[j];
        }
        __syncthreads();   // sync_b: h,sp,u of layer l+1 visible
    }

    // ---------------- output layer (64 -> 3), k split by half ----------------
    {
        float o0 = 0.f, o1 = 0.f, o2 = 0.f;
        if (state == 0 && half == 0) { o0 = b_out[0]; o1 = b_out[1]; o2 = b_out[2]; }
        const int k0 = jb;
        if (state == 0) {
            #pragma unroll 2
            for (int k = k0; k < k0 + 32; ++k) {
                const float m = sh_h[k*SAMP + samp];
                o0 = fmaf(m, W_out[k*3+0], o0);
                o1 = fmaf(m, W_out[k*3+1], o1);
                o2 = fmaf(m, W_out[k*3+2], o2);
            }
        } else {
            #pragma unroll 2
            for (int k = k0; k < k0 + 32; ++k) {
                const float m = sh_sp[k*SAMP + samp] * myT[k*SAMP + samp];
                o0 = fmaf(m, W_out[k*3+0], o0);
                o1 = fmaf(m, W_out[k*3+1], o1);
                o2 = fmaf(m, W_out[k*3+2], o2);
            }
        }
        sh_st[(wave*3+0)*SAMP + samp] = o0;
        sh_st[(wave*3+1)*SAMP + samp] = o1;
        sh_st[(wave*3+2)*SAMP + samp] = o2;
    }
    __syncthreads();
    if (wave == 0) {
        float T0 = sh_st[(0*3+0)*SAMP+samp] + sh_st[(1*3+0)*SAMP+samp];
        float T1 = sh_st[(0*3+1)*SAMP+samp] + sh_st[(1*3+1)*SAMP+samp];
        float T2 = sh_st[(0*3+2)*SAMP+samp] + sh_st[(1*3+2)*SAMP+samp];
        float a0 = sh_st[(2*3+0)*SAMP+samp] + sh_st[(3*3+0)*SAMP+samp];
        float a1 = sh_st[(2*3+1)*SAMP+samp] + sh_st[(3*3+1)*SAMP+samp];
        float a2 = sh_st[(2*3+2)*SAMP+samp] + sh_st[(3*3+2)*SAMP+samp];
        float c0 = sh_st[(4*3+0)*SAMP+samp] + sh_st[(5*3+0)*SAMP+samp];
        float c1 = sh_st[(4*3+1)*SAMP+samp] + sh_st[(5*3+1)*SAMP+samp];
        float c2 = sh_st[(4*3+2)*SAMP+samp] + sh_st[(5*3+2)*SAMP+samp];
        // wi3 = [T0, T1, softplus(T2)]; normalize; wi = wi3[:2]/n
        // (full-precision math here: 1 wave, negligible cost, detJ-sensitive)
        float sg2 = 1.f / (1.f + expf(-T2));               // d softplus / dT2
        float u2  = fmaxf(T2, 0.f) + log1pf(expf(-fabsf(T2)));
        float u0 = T0, u1 = T1;
        float n2  = u0*u0 + u1*u1 + u2*u2;
        float n   = fmaxf(sqrtf(n2), 1e-12f);
        float inv = 1.f / n;
        // JVP through softplus + normalize: dwi_i = inv*(du_i - u_i*(u.du)/n2)
        float da2 = sg2 * a2, dc2 = sg2 * c2;
        float ka  = (u0*a0 + u1*a1 + u2*da2) / n2;
        float kc  = (u0*c0 + u1*c1 + u2*dc2) / n2;
        float d0x = (a0 - u0*ka) * inv;
        float d0y = (a1 - u1*ka) * inv;
        float d1x = (c0 - u0*kc) * inv;
        float d1y = (c1 - u1*kc) * inv;
        float detJ = d0x*d1y - d1x*d0y;
        sh_h[samp*3+0] = u0 * inv;      // h readers all finished Phase A
        sh_h[samp*3+1] = u1 * inv;
        sh_h[samp*3+2] = detJ;
    }
    __syncthreads();
    if (tid < 192) {
        out[blockIdx.x*192 + tid] = sh_h[tid];   // coalesced (B,3) write
    }
}

extern "C" void kernel_launch(void* const* d_in, const int* in_sizes, int n_in,
                              void* d_out, int out_size, void* d_ws, size_t ws_size,
                              hipStream_t stream) {
    const float* wo    = (const float*)d_in[0];
    const float* zz    = (const float*)d_in[1];
    const float* W_in  = (const float*)d_in[2];
    const float* b_in  = (const float*)d_in[3];
    const float* W_hid = (const float*)d_in[4];
    const float* b_hid = (const float*)d_in[5];
    const float* W_out = (const float*)d_in[6];
    const float* b_out = (const float*)d_in[7];
    float* o = (float*)d_out;

    const int B = in_sizes[0] / 2;           // 524288
    const int nblk = B / SAMP;               // 8192
    neu_kernel<<<nblk, NTHR, 0, stream>>>(wo, zz, W_in, b_in, W_hid, b_hid,
                                          W_out, b_out, o);
}

// Round 9
// 628.712 us; speedup vs baseline: 1.5369x; 1.5369x over previous
//
#include <hip/hip_runtime.h>
#include <math.h>

// NeuReparam: fused posenc + 20->64->64->64->64->3 SiLU MLP forward + 2 JVPs
// + normalize/detJ epilogue.
//
// v3 design (post-mortem R4: 966us, VALUBusy 43%, 1 block/CU; VALU-busy time
// 415us vs 258us pure-FMA floor -> kill LDS/addr overhead AND occupancy):
//   * 3 waves/block (192 thr), 64 samples; wave0=primal, wave1/2=tangents.
//   * STATE IN REGISTERS: s[64] = h (primal) or t (tangent), fully-unrolled
//     static indexing. Inner loop = pure v_fmac(s[k], SGPR weight) - no
//     ds_read, no address arith. Matvec code SHARED by all 3 waves (I$ ~25KB,
//     l-loop NOT unrolled).
//   * Only cross-wave data: silu'(a) primal->tangents, via double-buffered
//     2x16KB LDS (sh_sp). ONE barrier per hidden layer (parity buffering
//     makes write(l+2) vs read(l) separated by barrier l+1). 4 barriers total.
//   * LDS 32.8KB, VGPR ~150 capped by __launch_bounds__(192,3)
//     -> ~4 blocks/CU = 12 waves/CU (2x round-4).
//   * Accumulator init folded into first k FMA (no v_mov burst).
//   * HW transcendentals (v_exp/v_rcp/v_sin/v_cos); full-precision epilogue.

#define SAMP 64
#define NTHR 192
#define C 64

__device__ __forceinline__ float frcp(float x) { return __builtin_amdgcn_rcpf(x); }
__device__ __forceinline__ float fsig(float a) { return frcp(1.f + __expf(-a)); }

__global__ __launch_bounds__(NTHR, 3) void neu_kernel(
    const float* __restrict__ wo, const float* __restrict__ z,
    const float* __restrict__ W_in, const float* __restrict__ b_in,
    const float* __restrict__ W_hid, const float* __restrict__ b_hid,
    const float* __restrict__ W_out, const float* __restrict__ b_out,
    float* __restrict__ out)
{
    __shared__ float sh_sp[2][C*SAMP];   // silu'(a) double buffer; [1] reused for staging

    const int tid  = threadIdx.x;
    const int samp = tid & 63;
    const int wave = __builtin_amdgcn_readfirstlane(tid >> 6);  // 0=P,1=T0,2=T1
    const int gs   = blockIdx.x * SAMP + samp;

    float s[C];   // state: h (wave0) or t (wave1/2) - static indexing only
    float u[C];   // matvec accumulator - static indexing only

    // ---------------- input layer (all waves; shared matvec; no barrier) -----
    {
        float x[20];
        const float2 wv = *reinterpret_cast<const float2*>(wo + gs*2);
        x[0] = wv.x; x[1] = wv.y;
        float f0 = wv.x, f1 = wv.y;
        #pragma unroll
        for (int i = 0; i < 4; ++i) {
            x[2+4*i+0] = __sinf(f0);
            x[2+4*i+1] = __sinf(f1);
            x[2+4*i+2] = __cosf(f0);
            x[2+4*i+3] = __cosf(f1);
            f0 += f0; f1 += f1;
        }
        const float2 zv = *reinterpret_cast<const float2*>(z + gs*2);
        x[18] = zv.x;
        x[19] = zv.y;

        #pragma unroll
        for (int c = 0; c < 2; ++c) {
            const int c0 = c * 32;
            // init: u = b + x0*W[0]  (bias folded, no mov burst)
            {
                const float* wr = W_in + 0*C + c0;
                #pragma unroll
                for (int j = 0; j < 32; ++j) u[c0+j] = fmaf(x[0], wr[j], b_in[c0+j]);
            }
            #pragma unroll
            for (int k = 1; k < 20; ++k) {
                const float xk = x[k];
                const float* wr = W_in + k*C + c0;
                #pragma unroll
                for (int j = 0; j < 32; ++j) u[c0+j] = fmaf(xk, wr[j], u[c0+j]);
            }
        }
        if (wave == 0) {
            #pragma unroll
            for (int j = 0; j < 64; ++j) {
                float a = u[j];
                s[j] = a * fsig(a);
            }
        } else {
            const float* wr = W_in + (17 + wave)*C;   // row 18 (dz0) / 19 (dz1)
            #pragma unroll
            for (int j = 0; j < 64; ++j) {
                float a  = u[j];
                float sg = fsig(a);
                float sp = sg * (1.f + a * (1.f - sg));
                s[j] = sp * wr[j];
            }
        }
    }

    // ---------------- hidden layers (1 barrier each) ----------------
    for (int l = 0; l < 3; ++l) {
        const float* Wl = W_hid + l*C*C;
        // shared matvec: u = Wl^T s  (pure register FMA, SGPR weights)
        #pragma unroll
        for (int c = 0; c < 2; ++c) {
            const int c0 = c * 32;
            {   // init with k=0 (no mov burst)
                const float s0 = s[0];
                const float* wr = Wl + c0;
                #pragma unroll
                for (int j = 0; j < 32; ++j) u[c0+j] = s0 * wr[j];
            }
            #pragma unroll
            for (int k = 1; k < C; ++k) {
                const float sk = s[k];
                const float* wr = Wl + k*C + c0;
                #pragma unroll
                for (int j = 0; j < 32; ++j) u[c0+j] = fmaf(sk, wr[j], u[c0+j]);
            }
        }
        float* buf = sh_sp[l & 1];
        if (wave == 0) {
            const float* bh = b_hid + l*C;
            #pragma unroll
            for (int j = 0; j < 64; ++j) {
                float a  = u[j] + bh[j];
                float sg = fsig(a);
                s[j] = a * sg;                                    // h_new
                buf[j*SAMP + samp] = sg * (1.f + a * (1.f - sg)); // sp_new
            }
        }
        __syncthreads();   // sp(l) visible; also orders T reads(l) vs P write(l+2)
        if (wave != 0) {
            #pragma unroll
            for (int j = 0; j < 64; ++j) {
                s[j] = buf[j*SAMP + samp] * u[j];                 // t_new = sp*u
            }
        }
    }

    // ---------------- output layer (64 -> 3, all waves, shared) ----------------
    {
        float o0, o1, o2;
        if (wave == 0) { o0 = b_out[0]; o1 = b_out[1]; o2 = b_out[2]; }
        else           { o0 = 0.f;      o1 = 0.f;      o2 = 0.f;      }
        #pragma unroll
        for (int k = 0; k < C; ++k) {
            o0 = fmaf(s[k], W_out[k*3+0], o0);
            o1 = fmaf(s[k], W_out[k*3+1], o1);
            o2 = fmaf(s[k], W_out[k*3+2], o2);
        }
        // stage into sh_sp[1] (its last reader finished before barrier(l=2))
        float* st = sh_sp[1];
        st[(wave*3+0)*SAMP + samp] = o0;
        st[(wave*3+1)*SAMP + samp] = o1;
        st[(wave*3+2)*SAMP + samp] = o2;
    }
    __syncthreads();
    if (wave == 0) {
        const float* st = sh_sp[1];
        float T0 = st[0*SAMP+samp], T1 = st[1*SAMP+samp], T2 = st[2*SAMP+samp];
        float a0 = st[3*SAMP+samp], a1 = st[4*SAMP+samp], a2 = st[5*SAMP+samp];
        float c0 = st[6*SAMP+samp], c1 = st[7*SAMP+samp], c2 = st[8*SAMP+samp];
        // wi3 = [T0, T1, softplus(T2)]; normalize; wi = wi3[:2]/n
        // full-precision math (1 wave, detJ-sensitive)
        float sg2 = 1.f / (1.f + expf(-T2));               // d softplus / dT2
        float u2  = fmaxf(T2, 0.f) + log1pf(expf(-fabsf(T2)));
        float u0 = T0, u1 = T1;
        float n2  = u0*u0 + u1*u1 + u2*u2;
        float n   = fmaxf(sqrtf(n2), 1e-12f);
        float inv = 1.f / n;
        // JVP through softplus + normalize: dwi_i = inv*(du_i - u_i*(u.du)/n2)
        float da2 = sg2 * a2, dc2 = sg2 * c2;
        float ka  = (u0*a0 + u1*a1 + u2*da2) / n2;
        float kc  = (u0*c0 + u1*c1 + u2*dc2) / n2;
        float d0x = (a0 - u0*ka) * inv;
        float d0y = (a1 - u1*ka) * inv;
        float d1x = (c0 - u0*kc) * inv;
        float d1y = (c1 - u1*kc) * inv;
        float detJ = d0x*d1y - d1x*d0y;
        out[gs*3+0] = u0 * inv;          // 768B contiguous per wave
        out[gs*3+1] = u1 * inv;
        out[gs*3+2] = detJ;
    }
}

extern "C" void kernel_launch(void* const* d_in, const int* in_sizes, int n_in,
                              void* d_out, int out_size, void* d_ws, size_t ws_size,
                              hipStream_t stream) {
    const float* wo    = (const float*)d_in[0];
    const float* zz    = (const float*)d_in[1];
    const float* W_in  = (const float*)d_in[2];
    const float* b_in  = (const float*)d_in[3];
    const float* W_hid = (const float*)d_in[4];
    const float* b_hid = (const float*)d_in[5];
    const float* W_out = (const float*)d_in[6];
    const float* b_out = (const float*)d_in[7];
    float* o = (float*)d_out;

    const int B = in_sizes[0] / 2;           // 524288
    const int nblk = B / SAMP;               // 8192
    neu_kernel<<<nblk, NTHR, 0, stream>>>(wo, zz, W_in, b_in, W_hid, b_hid,
                                          W_out, b_out, o);
}

// Round 10
// 623.313 us; speedup vs baseline: 1.5502x; 1.0087x over previous
//
#include <hip/hip_runtime.h>
#include <math.h>

// NeuReparam: fused posenc + 20->64->64->64->64->3 SiLU MLP forward + 2 JVPs
// + normalize/detJ epilogue.
//
// v4 (post-mortem R9: 628us, VALUBusy 57%, Occ 31%, VGPR 72 -> AGPR-spilled
// ~144 unified regs => 3 waves/SIMD register cap; idle 273us dominates):
//   * 3 waves/block (192 thr): wave0=primal, wave1/2=tangents. 64 samples.
//   * Register diet to reach 4 waves/SIMD (goal <=128 unified):
//     s[0..48) in regs, s[48..64) in 12KB wave-private LDS scratch (sh_sx).
//     Matvec is K-MAJOR: s[k] dies as u[64] fills -> peak ~112-124 regs.
//     K-major also reads each 256B weight row ONCE per wave (K$ pressure /2).
//   * Exchange LDS: single 16KB a-buffer (raw pre-activation, bias included).
//     Tangents compute their own silu'(a) -> balanced barrier sections.
//     2 barriers/layer (write->bar1->read, reads->bar2->next write). 7 total.
//   * LDS 28672B -> 5 blocks/CU (143KB); __launch_bounds__(192,4) caps regs
//     at 128 -> 15 waves/CU (47%) vs 12 now.
//   * HW transcendentals (v_exp/v_rcp/v_sin/v_cos); full-precision epilogue.

#define SAMP 64
#define NTHR 192
#define C 64
#define JR 48            // s channels in registers
#define JS (C - JR)      // 16 channels in LDS scratch

__device__ __forceinline__ float frcp(float x) { return __builtin_amdgcn_rcpf(x); }
__device__ __forceinline__ float fsig(float a) { return frcp(1.f + __expf(-a)); }
__device__ __forceinline__ float fsp(float a, float sg) {  // silu'(a) given sigmoid
    return sg * (1.f + a * (1.f - sg));
}

__global__ __launch_bounds__(NTHR, 4) void neu_kernel(
    const float* __restrict__ wo, const float* __restrict__ z,
    const float* __restrict__ W_in, const float* __restrict__ b_in,
    const float* __restrict__ W_hid, const float* __restrict__ b_hid,
    const float* __restrict__ W_out, const float* __restrict__ b_out,
    float* __restrict__ out)
{
    __shared__ float sh_a[C*SAMP];        // 16KB: primal pre-activation; reused for staging
    __shared__ float sh_sx[3][JS*SAMP];   // 12KB: per-wave private s-overflow (16ch x 64samp)

    const int tid  = threadIdx.x;
    const int samp = tid & 63;
    const int wave = __builtin_amdgcn_readfirstlane(tid >> 6);  // 0=P,1=T0,2=T1
    const int gs   = blockIdx.x * SAMP + samp;

    float* sx = sh_sx[wave];   // wave-uniform base

    float s[JR];   // state channels [0,48)  - static indexing only
    float u[C];    // matvec accumulator     - static indexing only

    // ---------------- input layer (all waves; no barrier) ----------------
    {
        float x[20];
        const float2 wv = *reinterpret_cast<const float2*>(wo + gs*2);
        x[0] = wv.x; x[1] = wv.y;
        float f0 = wv.x, f1 = wv.y;
        #pragma unroll
        for (int i = 0; i < 4; ++i) {
            x[2+4*i+0] = __sinf(f0);
            x[2+4*i+1] = __sinf(f1);
            x[2+4*i+2] = __cosf(f0);
            x[2+4*i+3] = __cosf(f1);
            f0 += f0; f1 += f1;
        }
        const float2 zv = *reinterpret_cast<const float2*>(z + gs*2);
        x[18] = zv.x;
        x[19] = zv.y;

        {   // u = b_in + x0*W_in[0]
            const float* wr = W_in;
            #pragma unroll
            for (int j = 0; j < C; ++j) u[j] = fmaf(x[0], wr[j], b_in[j]);
        }
        #pragma unroll
        for (int k = 1; k < 20; ++k) {
            const float xk = x[k];
            const float* wr = W_in + k*C;
            #pragma unroll
            for (int j = 0; j < C; ++j) u[j] = fmaf(xk, wr[j], u[j]);
        }
        if (wave == 0) {
            #pragma unroll
            for (int j = 0; j < JR; ++j) { float a = u[j]; s[j] = a * fsig(a); }
            #pragma unroll
            for (int j = JR; j < C; ++j) { float a = u[j]; sx[(j-JR)*SAMP+samp] = a * fsig(a); }
        } else {
            const float* wr = W_in + (17 + wave)*C;   // row 18 (dz0) / 19 (dz1)
            #pragma unroll
            for (int j = 0; j < JR; ++j) {
                float a = u[j], sg = fsig(a);
                s[j] = fsp(a, sg) * wr[j];
            }
            #pragma unroll
            for (int j = JR; j < C; ++j) {
                float a = u[j], sg = fsig(a);
                sx[(j-JR)*SAMP+samp] = fsp(a, sg) * wr[j];
            }
        }
    }

    // ---------------- hidden layers (2 barriers each) ----------------
    for (int l = 0; l < 3; ++l) {
        const float* Wl = W_hid + l*C*C;
        // phase 1: k in [0,JR) from registers; s[k] dies as consumed
        {
            const float m0 = s[0];
            const float* wr = Wl;
            #pragma unroll
            for (int j = 0; j < C; ++j) u[j] = m0 * wr[j];
        }
        #pragma unroll
        for (int k = 1; k < JR; ++k) {
            const float m = s[k];
            const float* wr = Wl + k*C;
            #pragma unroll
            for (int j = 0; j < C; ++j) u[j] = fmaf(m, wr[j], u[j]);
        }
        // phase 2: k in [JR,C) from LDS scratch
        {
            float st[JS];
            #pragma unroll
            for (int i = 0; i < JS; ++i) st[i] = sx[i*SAMP + samp];
            #pragma unroll
            for (int k = JR; k < C; ++k) {
                const float m = st[k-JR];
                const float* wr = Wl + k*C;
                #pragma unroll
                for (int j = 0; j < C; ++j) u[j] = fmaf(m, wr[j], u[j]);
            }
        }
        if (wave == 0) {
            const float* bh = b_hid + l*C;
            #pragma unroll
            for (int j = 0; j < C; ++j) u[j] += bh[j];
            #pragma unroll
            for (int j = 0; j < C; ++j) sh_a[j*SAMP + samp] = u[j];
        }
        __syncthreads();   // bar1: a visible
        if (wave == 0) {
            #pragma unroll
            for (int j = 0; j < JR; ++j) { float a = u[j]; s[j] = a * fsig(a); }
            #pragma unroll
            for (int j = JR; j < C; ++j) { float a = u[j]; sx[(j-JR)*SAMP+samp] = a * fsig(a); }
        } else {
            #pragma unroll
            for (int j = 0; j < JR; ++j) {
                float a = sh_a[j*SAMP + samp], sg = fsig(a);
                s[j] = fsp(a, sg) * u[j];
            }
            #pragma unroll
            for (int j = JR; j < C; ++j) {
                float a = sh_a[j*SAMP + samp], sg = fsig(a);
                sx[(j-JR)*SAMP+samp] = fsp(a, sg) * u[j];
            }
        }
        __syncthreads();   // bar2: tangent a-reads done -> next a-write safe
    }

    // ---------------- output layer (64 -> 3, all waves) ----------------
    {
        float o0, o1, o2;
        if (wave == 0) { o0 = b_out[0]; o1 = b_out[1]; o2 = b_out[2]; }
        else           { o0 = 0.f;      o1 = 0.f;      o2 = 0.f;      }
        #pragma unroll
        for (int k = 0; k < JR; ++k) {
            o0 = fmaf(s[k], W_out[k*3+0], o0);
            o1 = fmaf(s[k], W_out[k*3+1], o1);
            o2 = fmaf(s[k], W_out[k*3+2], o2);
        }
        float st[JS];
        #pragma unroll
        for (int i = 0; i < JS; ++i) st[i] = sx[i*SAMP + samp];
        #pragma unroll
        for (int k = JR; k < C; ++k) {
            o0 = fmaf(st[k-JR], W_out[k*3+0], o0);
            o1 = fmaf(st[k-JR], W_out[k*3+1], o1);
            o2 = fmaf(st[k-JR], W_out[k*3+2], o2);
        }
        // stage into sh_a (all a-reads finished at bar2 of l=2)
        sh_a[(wave*3+0)*SAMP + samp] = o0;
        sh_a[(wave*3+1)*SAMP + samp] = o1;
        sh_a[(wave*3+2)*SAMP + samp] = o2;
    }
    __syncthreads();
    if (wave == 0) {
        float T0 = sh_a[0*SAMP+samp], T1 = sh_a[1*SAMP+samp], T2 = sh_a[2*SAMP+samp];
        float a0 = sh_a[3*SAMP+samp], a1 = sh_a[4*SAMP+samp], a2 = sh_a[5*SAMP+samp];
        float c0 = sh_a[6*SAMP+samp], c1 = sh_a[7*SAMP+samp], c2 = sh_a[8*SAMP+samp];
        // wi3 = [T0, T1, softplus(T2)]; normalize; wi = wi3[:2]/n
        // full-precision math (1 wave, detJ-sensitive)
        float sg2 = 1.f / (1.f + expf(-T2));               // d softplus / dT2
        float u2  = fmaxf(T2, 0.f) + log1pf(expf(-fabsf(T2)));
        float u0 = T0, u1 = T1;
        float n2  = u0*u0 + u1*u1 + u2*u2;
        float n   = fmaxf(sqrtf(n2), 1e-12f);
        float inv = 1.f / n;
        // JVP through softplus + normalize: dwi_i = inv*(du_i - u_i*(u.du)/n2)
        float da2 = sg2 * a2, dc2 = sg2 * c2;
        float ka  = (u0*a0 + u1*a1 + u2*da2) / n2;
        float kc  = (u0*c0 + u1*c1 + u2*dc2) / n2;
        float d0x = (a0 - u0*ka) * inv;
        float d0y = (a1 - u1*ka) * inv;
        float d1x = (c0 - u0*kc) * inv;
        float d1y = (c1 - u1*kc) * inv;
        float detJ = d0x*d1y - d1x*d0y;
        out[gs*3+0] = u0 * inv;          // 768B contiguous per wave
        out[gs*3+1] = u1 * inv;
        out[gs*3+2] = detJ;
    }
}

extern "C" void kernel_launch(void* const* d_in, const int* in_sizes, int n_in,
                              void* d_out, int out_size, void* d_ws, size_t ws_size,
                              hipStream_t stream) {
    const float* wo    = (const float*)d_in[0];
    const float* zz    = (const float*)d_in[1];
    const float* W_in  = (const float*)d_in[2];
    const float* b_in  = (const float*)d_in[3];
    const float* W_hid = (const float*)d_in[4];
    const float* b_hid = (const float*)d_in[5];
    const float* W_out = (const float*)d_in[6];
    const float* b_out = (const float*)d_in[7];
    float* o = (float*)d_out;

    const int B = in_sizes[0] / 2;           // 524288
    const int nblk = B / SAMP;               // 8192
    neu_kernel<<<nblk, NTHR, 0, stream>>>(wo, zz, W_in, b_in, W_hid, b_hid,
                                          W_out, b_out, o);
}

// Round 13
// 582.656 us; speedup vs baseline: 1.6584x; 1.0698x over previous
//
#include <hip/hip_runtime.h>
#include <math.h>

// NeuReparam: fused posenc + 20->64->64->64->64->3 SiLU MLP forward + 2 JVPs
// + normalize/detJ epilogue.
//
// v5b (v5 + compile fix: builtin 'h' element type is __fp16 on this ROCm, so
// half2_t must be __fp16 ext_vector(2) to match cvt_pkrtz/fdot2 signatures).
//
// v5 (post-mortem R10: 652us FLAT vs v3 despite Occ 31->40, VALUBusy 57->66:
// kernel is VALU-INSTRUCTION-COUNT bound; only inst removal moves dur):
//   * Matvec via v_dot2_f32_f16 (__builtin_amdgcn_fdot2): 2 MACs/inst,
//     fp32 accumulate -> matvec issue cycles HALVED (13.8k -> 6.9k insts).
//   * Weights pre-packed to half2 k-pairs in d_ws by a tiny pre-kernel
//     (27.5KB, runs every launch; graph-capture safe). Activations packed
//     with v_cvt_pkrtz_f16_f32 (32 insts/layer).
//   * Packed state = 32 u32 regs -> NO s-overflow LDS scratch; LDS = 16.4KB
//     (sh_a exchange only). __launch_bounds__(192,4): reg cap 128,
//     5 blocks/CU, 4 waves/SIMD.
//   * 3 waves/block: wave0=primal, wave1/2=tangents; 64 samples/block.
//     2 barriers/layer as v4. fp32 epilogue (detJ-sensitive) unchanged.
//   * Precision: fp16 inputs (11-bit mantissa, rel 2.4e-4), fp32 accum.
//     absmax expected 2-5e-3 (was 9.8e-4) - tolerance gamble, info either way.

#define SAMP 64
#define NTHR 192
#define C 64

typedef __fp16 half2_t __attribute__((ext_vector_type(2)));

__device__ __forceinline__ float frcp(float x) { return __builtin_amdgcn_rcpf(x); }
__device__ __forceinline__ float fsig(float a) { return frcp(1.f + __expf(-a)); }
__device__ __forceinline__ float fsp(float a, float sg) {  // silu'(a)
    return sg * (1.f + a * (1.f - sg));
}
__device__ __forceinline__ half2_t pk(float lo, float hi) {
    return __builtin_amdgcn_cvt_pkrtz(lo, hi);
}
__device__ __forceinline__ float fdot2(half2_t a, half2_t b, float c) {
#if __has_builtin(__builtin_amdgcn_fdot2)
    return __builtin_amdgcn_fdot2(a, b, c, false);
#else
    return fmaf((float)a.x, (float)b.x, fmaf((float)a.y, (float)b.y, c));
#endif
}

// ---- weight packing layout in d_ws (half2 elements) ----
// wp_in : [p<10][j<64]          pack(W_in[2p][j],  W_in[2p+1][j])      @ 0
// wp_hid: [l<3][p<32][j<64]     pack(W_hid[l][2p][j], W_hid[l][2p+1][j]) @ 640
// wp_out: [p<32][i<3]           pack(W_out[2p][i], W_out[2p+1][i])     @ 6784
#define WP_HID 640
#define WP_OUT 6784
#define WP_TOT 6880

__global__ void pack_kernel(const float* __restrict__ W_in,
                            const float* __restrict__ W_hid,
                            const float* __restrict__ W_out,
                            half2_t* __restrict__ wp)
{
    int i = blockIdx.x * 256 + threadIdx.x;
    if (i < WP_HID) {
        int p = i >> 6, j = i & 63;
        wp[i] = pk(W_in[(2*p)*C + j], W_in[(2*p+1)*C + j]);
    } else if (i < WP_OUT) {
        int t = i - WP_HID;
        int l = t >> 11, r = t & 2047, p = r >> 6, j = r & 63;
        wp[i] = pk(W_hid[l*C*C + (2*p)*C + j], W_hid[l*C*C + (2*p+1)*C + j]);
    } else if (i < WP_TOT) {
        int t = i - WP_OUT;
        int p = t / 3, q = t - p*3;
        wp[i] = pk(W_out[(2*p)*3 + q], W_out[(2*p+1)*3 + q]);
    }
}

__global__ __launch_bounds__(NTHR, 4) void neu_kernel(
    const float* __restrict__ wo, const float* __restrict__ z,
    const float* __restrict__ W_in, const float* __restrict__ b_in,
    const float* __restrict__ b_hid, const float* __restrict__ b_out,
    const half2_t* __restrict__ wp,
    float* __restrict__ out)
{
    __shared__ float sh_a[C*SAMP];   // 16KB: primal pre-activation; reused for staging

    const int tid  = threadIdx.x;
    const int samp = tid & 63;
    const int wave = __builtin_amdgcn_readfirstlane(tid >> 6);  // 0=P,1=T0,2=T1
    const int gs   = blockIdx.x * SAMP + samp;

    float   u[C];     // matvec accumulator (fp32) - static indexing only
    half2_t spk[32];  // packed state (h or t), channel pairs - static indexing

    // ---------------- input layer (all waves; no barrier) ----------------
    {
        float x[20];
        const float2 wv = *reinterpret_cast<const float2*>(wo + gs*2);
        x[0] = wv.x; x[1] = wv.y;
        float f0 = wv.x, f1 = wv.y;
        #pragma unroll
        for (int i = 0; i < 4; ++i) {
            x[2+4*i+0] = __sinf(f0);
            x[2+4*i+1] = __sinf(f1);
            x[2+4*i+2] = __cosf(f0);
            x[2+4*i+3] = __cosf(f1);
            f0 += f0; f1 += f1;
        }
        const float2 zv = *reinterpret_cast<const float2*>(z + gs*2);
        x[18] = zv.x;
        x[19] = zv.y;

        half2_t xp[10];
        #pragma unroll
        for (int p = 0; p < 10; ++p) xp[p] = pk(x[2*p], x[2*p+1]);

        {   // u = b_in + dot2(xp0, w0)
            const half2_t* wr = wp;
            #pragma unroll
            for (int j = 0; j < C; ++j) u[j] = fdot2(xp[0], wr[j], b_in[j]);
        }
        #pragma unroll
        for (int p = 1; p < 10; ++p) {
            const half2_t* wr = wp + p*C;
            #pragma unroll
            for (int j = 0; j < C; ++j) u[j] = fdot2(xp[p], wr[j], u[j]);
        }
        if (wave == 0) {
            #pragma unroll
            for (int p = 0; p < 32; ++p) {
                float a0 = u[2*p],   h0 = a0 * fsig(a0);
                float a1 = u[2*p+1], h1 = a1 * fsig(a1);
                spk[p] = pk(h0, h1);
            }
        } else {
            const float* wr = W_in + (17 + wave)*C;   // fp32 row 18 (dz0) / 19 (dz1)
            #pragma unroll
            for (int p = 0; p < 32; ++p) {
                float a0 = u[2*p],   t0 = fsp(a0, fsig(a0)) * wr[2*p];
                float a1 = u[2*p+1], t1 = fsp(a1, fsig(a1)) * wr[2*p+1];
                spk[p] = pk(t0, t1);
            }
        }
    }

    // ---------------- hidden layers (2 barriers each) ----------------
    for (int l = 0; l < 3; ++l) {
        const half2_t* Wl = wp + WP_HID + l*32*C;
        {   // p = 0 init (no mov burst)
            const half2_t m0 = spk[0];
            #pragma unroll
            for (int j = 0; j < C; ++j) u[j] = fdot2(m0, Wl[j], 0.f);
        }
        #pragma unroll
        for (int p = 1; p < 32; ++p) {
            const half2_t m = spk[p];
            const half2_t* wr = Wl + p*C;
            #pragma unroll
            for (int j = 0; j < C; ++j) u[j] = fdot2(m, wr[j], u[j]);
        }
        if (wave == 0) {
            const float* bh = b_hid + l*C;
            #pragma unroll
            for (int j = 0; j < C; ++j) u[j] += bh[j];
            #pragma unroll
            for (int j = 0; j < C; ++j) sh_a[j*SAMP + samp] = u[j];
        }
        __syncthreads();   // bar1: a visible
        if (wave == 0) {
            #pragma unroll
            for (int p = 0; p < 32; ++p) {
                float a0 = u[2*p],   h0 = a0 * fsig(a0);
                float a1 = u[2*p+1], h1 = a1 * fsig(a1);
                spk[p] = pk(h0, h1);
            }
        } else {
            #pragma unroll
            for (int p = 0; p < 32; ++p) {
                float a0 = sh_a[(2*p)*SAMP + samp];
                float a1 = sh_a[(2*p+1)*SAMP + samp];
                float t0 = fsp(a0, fsig(a0)) * u[2*p];
                float t1 = fsp(a1, fsig(a1)) * u[2*p+1];
                spk[p] = pk(t0, t1);
            }
        }
        __syncthreads();   // bar2: tangent a-reads done -> next a-write safe
    }

    // ---------------- output layer (64 -> 3, all waves, packed) ------------
    {
        float o0, o1, o2;
        if (wave == 0) { o0 = b_out[0]; o1 = b_out[1]; o2 = b_out[2]; }
        else           { o0 = 0.f;      o1 = 0.f;      o2 = 0.f;      }
        const half2_t* wr = wp + WP_OUT;
        #pragma unroll
        for (int p = 0; p < 32; ++p) {
            o0 = fdot2(spk[p], wr[p*3+0], o0);
            o1 = fdot2(spk[p], wr[p*3+1], o1);
            o2 = fdot2(spk[p], wr[p*3+2], o2);
        }
        // stage into sh_a (all a-reads finished at bar2 of l=2)
        sh_a[(wave*3+0)*SAMP + samp] = o0;
        sh_a[(wave*3+1)*SAMP + samp] = o1;
        sh_a[(wave*3+2)*SAMP + samp] = o2;
    }
    __syncthreads();
    if (wave == 0) {
        float T0 = sh_a[0*SAMP+samp], T1 = sh_a[1*SAMP+samp], T2 = sh_a[2*SAMP+samp];
        float a0 = sh_a[3*SAMP+samp], a1 = sh_a[4*SAMP+samp], a2 = sh_a[5*SAMP+samp];
        float c0 = sh_a[6*SAMP+samp], c1 = sh_a[7*SAMP+samp], c2 = sh_a[8*SAMP+samp];
        // wi3 = [T0, T1, softplus(T2)]; normalize; wi = wi3[:2]/n
        // full-precision math (1 wave, detJ-sensitive)
        float sg2 = 1.f / (1.f + expf(-T2));               // d softplus / dT2
        float u2  = fmaxf(T2, 0.f) + log1pf(expf(-fabsf(T2)));
        float u0 = T0, u1 = T1;
        float n2  = u0*u0 + u1*u1 + u2*u2;
        float n   = fmaxf(sqrtf(n2), 1e-12f);
        float inv = 1.f / n;
        // JVP through softplus + normalize: dwi_i = inv*(du_i - u_i*(u.du)/n2)
        float da2 = sg2 * a2, dc2 = sg2 * c2;
        float ka  = (u0*a0 + u1*a1 + u2*da2) / n2;
        float kc  = (u0*c0 + u1*c1 + u2*dc2) / n2;
        float d0x = (a0 - u0*ka) * inv;
        float d0y = (a1 - u1*ka) * inv;
        float d1x = (c0 - u0*kc) * inv;
        float d1y = (c1 - u1*kc) * inv;
        float detJ = d0x*d1y - d1x*d0y;
        out[gs*3+0] = u0 * inv;          // 768B contiguous per wave
        out[gs*3+1] = u1 * inv;
        out[gs*3+2] = detJ;
    }
}

extern "C" void kernel_launch(void* const* d_in, const int* in_sizes, int n_in,
                              void* d_out, int out_size, void* d_ws, size_t ws_size,
                              hipStream_t stream) {
    const float* wo    = (const float*)d_in[0];
    const float* zz    = (const float*)d_in[1];
    const float* W_in  = (const float*)d_in[2];
    const float* b_in  = (const float*)d_in[3];
    const float* W_hid = (const float*)d_in[4];
    const float* b_hid = (const float*)d_in[5];
    const float* W_out = (const float*)d_in[6];
    const float* b_out = (const float*)d_in[7];
    float* o = (float*)d_out;
    half2_t* wp = (half2_t*)d_ws;

    pack_kernel<<<(WP_TOT + 255)/256, 256, 0, stream>>>(W_in, W_hid, W_out, wp);

    const int B = in_sizes[0] / 2;           // 524288
    const int nblk = B / SAMP;               // 8192
    neu_kernel<<<nblk, NTHR, 0, stream>>>(wo, zz, W_in, b_in, b_hid, b_out,
                                          wp, o);
}